// Round 1
// baseline (558.765 us; speedup 1.0000x reference)
//
#include <hip/hip_runtime.h>
#include <math.h>

// GAT model: N=50000 nodes, E=500000 edges (+N self loops), D=128, layer1 heads=4.
// All f32. CSR-by-dst built on device once per launch (graph shared by all layers).

#define LEAKY(e) ((e) > 0.f ? (e) : 0.2f * (e))

// ---------------- CSR construction ----------------

__global__ void k_hist(const int* __restrict__ ei, int E, int N, int* __restrict__ deg) {
    int e = blockIdx.x * blockDim.x + threadIdx.x;
    int Et = E + N;
    if (e >= Et) return;
    int dst = (e < E) ? ei[2 * e + 1] : (e - E);
    atomicAdd(&deg[dst], 1);
}

__global__ void k_scan(const int* __restrict__ deg, int* __restrict__ row_ptr,
                       int* __restrict__ cursor, int n) {
    __shared__ int buf[1024];
    __shared__ int carry_s;
    int tid = threadIdx.x;
    if (tid == 0) carry_s = 0;
    __syncthreads();
    for (int base = 0; base < n; base += 1024) {
        int v = (base + tid < n) ? deg[base + tid] : 0;
        buf[tid] = v;
        __syncthreads();
        for (int off = 1; off < 1024; off <<= 1) {
            int t = (tid >= off) ? buf[tid - off] : 0;
            __syncthreads();
            buf[tid] += t;
            __syncthreads();
        }
        int excl = buf[tid] - v + carry_s;
        if (base + tid < n) { row_ptr[base + tid] = excl; cursor[base + tid] = excl; }
        __syncthreads();
        if (tid == 0) carry_s += buf[1023];
        __syncthreads();
    }
    if (tid == 0) row_ptr[n] = carry_s;
}

__global__ void k_scatter(const int* __restrict__ ei, int E, int N,
                          int* __restrict__ cursor, int* __restrict__ csr_src) {
    int e = blockIdx.x * blockDim.x + threadIdx.x;
    int Et = E + N;
    if (e >= Et) return;
    int src, dst;
    if (e < E) { src = ei[2 * e]; dst = ei[2 * e + 1]; }
    else { src = dst = e - E; }
    int pos = atomicAdd(&cursor[dst], 1);
    csr_src[pos] = src;
}

// ---------------- Layer-1 rank-1 constants ----------------
// consts layout (floats): u[128] @0, v[128] @128, P[4]@256, Q[4]@260, R[4]@264, S[4]@268

__global__ void k_emb(const float* __restrict__ W_emb, const float* __restrict__ b_emb,
                      const float* __restrict__ W1, const float* __restrict__ as1,
                      const float* __restrict__ ad1, float* __restrict__ consts) {
    __shared__ float su[128], sv[128];
    int f = threadIdx.x;  // 128 threads
    float u = 0.f, v = 0.f;
    for (int k = 0; k < 128; k++) {
        u += W_emb[k] * W1[k * 128 + f];
        v += b_emb[k] * W1[k * 128 + f];
    }
    su[f] = u; sv[f] = v;
    consts[f] = u; consts[128 + f] = v;
    __syncthreads();
    if (f < 4) {
        float P = 0.f, Q = 0.f, R = 0.f, S = 0.f;
        for (int j = 0; j < 32; j++) {
            float uu = su[f * 32 + j], vv = sv[f * 32 + j];
            float a = as1[f * 32 + j], d = ad1[f * 32 + j];
            P += uu * a; Q += vv * a; R += uu * d; S += vv * d;
        }
        consts[256 + f] = P; consts[260 + f] = Q; consts[264 + f] = R; consts[268 + f] = S;
    }
}

// Layer 1 aggregation: per-node scalars. S_out[n,h] = sum_e w_e * x[src_e], Sw[n,h] = sum_e w_e.
__global__ void k_agg1(const float* __restrict__ x, const int* __restrict__ row_ptr,
                       const int* __restrict__ csr_src, const float* __restrict__ consts,
                       float* __restrict__ S_out, float* __restrict__ Sw_out, int n) {
    int node = blockIdx.x * blockDim.x + threadIdx.x;
    if (node >= n) return;
    float P[4], Q[4], R[4], Sc[4];
#pragma unroll
    for (int h = 0; h < 4; h++) {
        P[h] = consts[256 + h]; Q[h] = consts[260 + h];
        R[h] = consts[264 + h]; Sc[h] = consts[268 + h];
    }
    float xd = x[node];
    float adv[4];
#pragma unroll
    for (int h = 0; h < 4; h++) adv[h] = xd * R[h] + Sc[h];
    int s0 = row_ptr[node], s1 = row_ptr[node + 1];

    float m[4] = {-INFINITY, -INFINITY, -INFINITY, -INFINITY};
    for (int i = s0; i < s1; i++) {
        float xs = x[csr_src[i]];
#pragma unroll
        for (int h = 0; h < 4; h++) {
            float e = LEAKY(xs * P[h] + Q[h] + adv[h]);
            m[h] = fmaxf(m[h], e);
        }
    }
    float den[4] = {0.f, 0.f, 0.f, 0.f};
    for (int i = s0; i < s1; i++) {
        float xs = x[csr_src[i]];
#pragma unroll
        for (int h = 0; h < 4; h++) {
            float e = LEAKY(xs * P[h] + Q[h] + adv[h]);
            den[h] += expf(e - m[h]);
        }
    }
    float inv[4];
#pragma unroll
    for (int h = 0; h < 4; h++) inv[h] = 1.f / (den[h] + 1e-16f);
    float S[4] = {0.f, 0.f, 0.f, 0.f}, Wt[4] = {0.f, 0.f, 0.f, 0.f};
    for (int i = s0; i < s1; i++) {
        float xs = x[csr_src[i]];
#pragma unroll
        for (int h = 0; h < 4; h++) {
            float e = LEAKY(xs * P[h] + Q[h] + adv[h]);
            float w = expf(e - m[h]) * inv[h];
            S[h] += w * xs; Wt[h] += w;
        }
    }
#pragma unroll
    for (int h = 0; h < 4; h++) {
        S_out[node * 4 + h] = S[h];
        Sw_out[node * 4 + h] = Wt[h];
    }
}

// h1[n,f] = relu(S[n,h(f)]*u[f] + Sw[n,h(f)]*v[f] + b1[f])
__global__ void k_h1(const float* __restrict__ S_out, const float* __restrict__ Sw,
                     const float* __restrict__ consts, const float* __restrict__ b1,
                     float* __restrict__ h, int n) {
    int idx = blockIdx.x * blockDim.x + threadIdx.x;
    if (idx >= n * 128) return;
    int node = idx >> 7, f = idx & 127;
    float val = S_out[node * 4 + (f >> 5)] * consts[f] +
                Sw[node * 4 + (f >> 5)] * consts[128 + f] + b1[f];
    h[idx] = fmaxf(val, 0.f);
}

// ---------------- GEMM: xp = h @ W (+ alpha epilogue), layers 2-4 ----------------
// 128x128 tile per block (256 threads), 8x8 per thread, K staged in 32-chunks.
__global__ __launch_bounds__(256) void k_gemm(const float* __restrict__ h, const float* __restrict__ W,
                                              const float* __restrict__ avs, const float* __restrict__ avd,
                                              float* __restrict__ xp, float* __restrict__ alpha_s,
                                              float* __restrict__ alpha_d, int n) {
    __shared__ float hT[32][132];  // [k][r], stride 132 (16B aligned rows, conflict-free reads)
    __shared__ float Wl[32][132];  // [k][c]
    int tid = threadIdx.x;
    int tx = tid & 15, ty = tid >> 4;
    int rb = blockIdx.x * 128;
    float acc[8][8];
#pragma unroll
    for (int r = 0; r < 8; r++)
#pragma unroll
        for (int c = 0; c < 8; c++) acc[r][c] = 0.f;

    for (int k0 = 0; k0 < 128; k0 += 32) {
        __syncthreads();
        // h tile, transposed: hT[k][r] = h[rb+r][k0+k]
        int kq = (tid & 7) * 4;
#pragma unroll
        for (int s = 0; s < 4; s++) {
            int r = (tid >> 3) + (s << 5);
            int gr = rb + r;
            float4 hv = (gr < n) ? *(const float4*)(h + (size_t)gr * 128 + k0 + kq)
                                 : make_float4(0.f, 0.f, 0.f, 0.f);
            hT[kq + 0][r] = hv.x; hT[kq + 1][r] = hv.y;
            hT[kq + 2][r] = hv.z; hT[kq + 3][r] = hv.w;
        }
        // W tile: Wl[k][c] = W[k0+k][c]
#pragma unroll
        for (int s = 0; s < 4; s++) {
            int f4 = tid + (s << 8);          // 0..1023
            int k = f4 >> 5, c4 = (f4 & 31) * 4;
            *(float4*)(&Wl[k][c4]) = *(const float4*)(W + (k0 + k) * 128 + c4);
        }
        __syncthreads();
#pragma unroll
        for (int k = 0; k < 32; k++) {
            float4 t0 = *(const float4*)(&hT[k][ty * 8]);
            float4 t1 = *(const float4*)(&hT[k][ty * 8 + 4]);
            float4 w0 = *(const float4*)(&Wl[k][tx * 4]);
            float4 w1 = *(const float4*)(&Wl[k][tx * 4 + 64]);
            float a[8] = {t0.x, t0.y, t0.z, t0.w, t1.x, t1.y, t1.z, t1.w};
            float b[8] = {w0.x, w0.y, w0.z, w0.w, w1.x, w1.y, w1.z, w1.w};
#pragma unroll
            for (int r = 0; r < 8; r++)
#pragma unroll
                for (int c = 0; c < 8; c++) acc[r][c] += a[r] * b[c];
        }
    }

    // store xp
#pragma unroll
    for (int r = 0; r < 8; r++) {
        int gr = rb + ty * 8 + r;
        if (gr < n) {
            float4 o0 = make_float4(acc[r][0], acc[r][1], acc[r][2], acc[r][3]);
            float4 o1 = make_float4(acc[r][4], acc[r][5], acc[r][6], acc[r][7]);
            *(float4*)(xp + (size_t)gr * 128 + tx * 4) = o0;
            *(float4*)(xp + (size_t)gr * 128 + tx * 4 + 64) = o1;
        }
    }
    // alpha epilogue: alpha_s[r] = sum_c xp[r][c]*avs[c]
    float asv[8], adv[8];
#pragma unroll
    for (int j = 0; j < 4; j++) {
        asv[j] = avs[tx * 4 + j];       asv[4 + j] = avs[tx * 4 + 64 + j];
        adv[j] = avd[tx * 4 + j];       adv[4 + j] = avd[tx * 4 + 64 + j];
    }
#pragma unroll
    for (int r = 0; r < 8; r++) {
        float ps = 0.f, pd = 0.f;
#pragma unroll
        for (int c = 0; c < 8; c++) { ps += acc[r][c] * asv[c]; pd += acc[r][c] * adv[c]; }
#pragma unroll
        for (int off = 1; off < 16; off <<= 1) {
            ps += __shfl_xor(ps, off, 16);
            pd += __shfl_xor(pd, off, 16);
        }
        int gr = rb + ty * 8 + r;
        if (tx == 0 && gr < n) { alpha_s[gr] = ps; alpha_d[gr] = pd; }
    }
}

// ---------------- Aggregation, layers 2-4: one wave per dst node ----------------
__global__ __launch_bounds__(256) void k_agg(const float* __restrict__ xp, const float* __restrict__ as,
                                             const float* __restrict__ ad, const int* __restrict__ row_ptr,
                                             const int* __restrict__ csr_src, const float* __restrict__ bias,
                                             float* __restrict__ out, int n, int do_relu) {
    int w = threadIdx.x >> 6, lane = threadIdx.x & 63;
    int node = blockIdx.x * 4 + w;
    if (node >= n) return;
    int s0 = row_ptr[node], s1 = row_ptr[node + 1];
    float adval = ad[node];

    // pass A: max
    float m = -INFINITY;
    for (int i = s0 + lane; i < s1; i += 64) {
        float e = LEAKY(as[csr_src[i]] + adval);
        m = fmaxf(m, e);
    }
#pragma unroll
    for (int off = 32; off > 0; off >>= 1) m = fmaxf(m, __shfl_xor(m, off, 64));

    // pass B: denom
    float den = 0.f;
    for (int i = s0 + lane; i < s1; i += 64) {
        float e = LEAKY(as[csr_src[i]] + adval);
        den += expf(e - m);
    }
#pragma unroll
    for (int off = 32; off > 0; off >>= 1) den += __shfl_xor(den, off, 64);
    float inv = 1.f / (den + 1e-16f);

    // pass C: accumulate messages; lane -> feature pair (f = 2*lane)
    float2 accv = make_float2(0.f, 0.f);
    const float2* xp2 = (const float2*)xp;
    for (int i = s0; i < s1; i++) {
        int src = csr_src[i];
        float e = LEAKY(as[src] + adval);
        float wt = expf(e - m) * inv;
        float2 v = xp2[(size_t)src * 64 + lane];
        accv.x += wt * v.x;
        accv.y += wt * v.y;
    }
    float2 b = ((const float2*)bias)[lane];
    float o0 = accv.x + b.x, o1 = accv.y + b.y;
    if (do_relu) { o0 = fmaxf(o0, 0.f); o1 = fmaxf(o1, 0.f); }
    ((float2*)out)[(size_t)node * 64 + lane] = make_float2(o0, o1);
}

// ---------------- launch ----------------

extern "C" void kernel_launch(void* const* d_in, const int* in_sizes, int n_in,
                              void* d_out, int out_size, void* d_ws, size_t ws_size,
                              hipStream_t stream) {
    const float* x     = (const float*)d_in[0];
    const int*   ei    = (const int*)d_in[1];
    const float* W_emb = (const float*)d_in[2];
    const float* b_emb = (const float*)d_in[3];
    const float* W1    = (const float*)d_in[4];
    const float* as1   = (const float*)d_in[5];
    const float* ad1   = (const float*)d_in[6];
    const float* b1    = (const float*)d_in[7];
    const float* Wl[3]  = {(const float*)d_in[8],  (const float*)d_in[12], (const float*)d_in[16]};
    const float* asl[3] = {(const float*)d_in[9],  (const float*)d_in[13], (const float*)d_in[17]};
    const float* adl[3] = {(const float*)d_in[10], (const float*)d_in[14], (const float*)d_in[18]};
    const float* bl[3]  = {(const float*)d_in[11], (const float*)d_in[15], (const float*)d_in[19]};
    float* out = (float*)d_out;

    int N = in_sizes[0];
    int E = in_sizes[1] / 2;
    int Et = E + N;

    char* ws = (char*)d_ws;
    size_t off = 0;
    auto alloc = [&](size_t bytes) { size_t p = off; off += (bytes + 255) & ~(size_t)255; return p; };
    int*   deg     = (int*)(ws + alloc((size_t)N * 4));
    int*   row_ptr = (int*)(ws + alloc((size_t)(N + 1) * 4));
    int*   cursor  = (int*)(ws + alloc((size_t)N * 4));
    int*   csr_src = (int*)(ws + alloc((size_t)Et * 4));
    float* consts  = (float*)(ws + alloc(272 * 4));
    float* S_out   = (float*)(ws + alloc((size_t)N * 4 * 4));
    float* Sw      = (float*)(ws + alloc((size_t)N * 4 * 4));
    float* alpha_s = (float*)(ws + alloc((size_t)N * 4));
    float* alpha_d = (float*)(ws + alloc((size_t)N * 4));
    float* hbuf    = (float*)(ws + alloc((size_t)N * 128 * 4));
    float* xp      = (float*)(ws + alloc((size_t)N * 128 * 4));

    hipMemsetAsync(deg, 0, (size_t)N * 4, stream);
    k_hist<<<(Et + 255) / 256, 256, 0, stream>>>(ei, E, N, deg);
    k_scan<<<1, 1024, 0, stream>>>(deg, row_ptr, cursor, N);
    k_scatter<<<(Et + 255) / 256, 256, 0, stream>>>(ei, E, N, cursor, csr_src);

    k_emb<<<1, 128, 0, stream>>>(W_emb, b_emb, W1, as1, ad1, consts);
    k_agg1<<<(N + 255) / 256, 256, 0, stream>>>(x, row_ptr, csr_src, consts, S_out, Sw, N);
    k_h1<<<((size_t)N * 128 + 255) / 256, 256, 0, stream>>>(S_out, Sw, consts, b1, hbuf, N);

    for (int l = 0; l < 3; l++) {
        k_gemm<<<(N + 127) / 128, 256, 0, stream>>>(hbuf, Wl[l], asl[l], adl[l],
                                                    xp, alpha_s, alpha_d, N);
        float* dst = (l == 2) ? out : hbuf;
        k_agg<<<(N + 3) / 4, 256, 0, stream>>>(xp, alpha_s, alpha_d, row_ptr, csr_src,
                                               bl[l], dst, N, (l < 2) ? 1 : 0);
    }
}

// Round 2
// 453.899 us; speedup vs baseline: 1.2310x; 1.2310x over previous
//
#include <hip/hip_runtime.h>
#include <math.h>

// GAT model: N=50000 nodes, E=500000 edges (+N self loops), D=128, layer1 heads=4.
// All f32. CSR-by-dst built on device once per launch (graph shared by all layers).

#define LEAKY(e) ((e) > 0.f ? (e) : 0.2f * (e))
#define SCAN_BLK 1024

// ---------------- CSR construction ----------------

__global__ void k_hist(const int* __restrict__ ei, int E, int N, int* __restrict__ deg) {
    int e = blockIdx.x * blockDim.x + threadIdx.x;
    int Et = E + N;
    if (e >= Et) return;
    int dst = (e < E) ? ei[2 * e + 1] : (e - E);
    atomicAdd(&deg[dst], 1);
}

// phase 1: per-block inclusive scan; write exclusive-within-block + block sums
__global__ __launch_bounds__(SCAN_BLK) void k_scan1(const int* __restrict__ deg,
                                                    int* __restrict__ tmp,
                                                    int* __restrict__ blocksum, int n) {
    __shared__ int buf[SCAN_BLK];
    int tid = threadIdx.x;
    int gid = blockIdx.x * SCAN_BLK + tid;
    int v = (gid < n) ? deg[gid] : 0;
    buf[tid] = v;
    __syncthreads();
#pragma unroll
    for (int off = 1; off < SCAN_BLK; off <<= 1) {
        int t = (tid >= off) ? buf[tid - off] : 0;
        __syncthreads();
        buf[tid] += t;
        __syncthreads();
    }
    if (gid < n) tmp[gid] = buf[tid] - v;
    if (tid == SCAN_BLK - 1) blocksum[blockIdx.x] = buf[tid];
}

// phase 2: scan the (<=256) block sums in one block
__global__ __launch_bounds__(256) void k_scan2(const int* __restrict__ blocksum,
                                               int* __restrict__ blockoff, int nb,
                                               int* __restrict__ row_ptr, int n) {
    __shared__ int buf[256];
    int tid = threadIdx.x;
    int v = (tid < nb) ? blocksum[tid] : 0;
    buf[tid] = v;
    __syncthreads();
#pragma unroll
    for (int off = 1; off < 256; off <<= 1) {
        int t = (tid >= off) ? buf[tid - off] : 0;
        __syncthreads();
        buf[tid] += t;
        __syncthreads();
    }
    if (tid < nb) blockoff[tid] = buf[tid] - v;
    if (tid == 255) row_ptr[n] = buf[tid];
}

// phase 3: add block offsets
__global__ void k_scan3(const int* __restrict__ tmp, const int* __restrict__ blockoff,
                        int* __restrict__ row_ptr, int* __restrict__ cursor, int n) {
    int gid = blockIdx.x * blockDim.x + threadIdx.x;
    if (gid >= n) return;
    int v = tmp[gid] + blockoff[gid / SCAN_BLK];
    row_ptr[gid] = v;
    cursor[gid] = v;
}

__global__ void k_scatter(const int* __restrict__ ei, int E, int N,
                          int* __restrict__ cursor, int* __restrict__ csr_src) {
    int e = blockIdx.x * blockDim.x + threadIdx.x;
    int Et = E + N;
    if (e >= Et) return;
    int src, dst;
    if (e < E) { src = ei[2 * e]; dst = ei[2 * e + 1]; }
    else { src = dst = e - E; }
    int pos = atomicAdd(&cursor[dst], 1);
    csr_src[pos] = src;
}

// ---------------- Layer-1 rank-1 constants ----------------
// consts layout (floats): u[128] @0, v[128] @128, P[4]@256, Q[4]@260, R[4]@264, S[4]@268

__global__ void k_emb(const float* __restrict__ W_emb, const float* __restrict__ b_emb,
                      const float* __restrict__ W1, const float* __restrict__ as1,
                      const float* __restrict__ ad1, float* __restrict__ consts) {
    __shared__ float su[128], sv[128];
    int f = threadIdx.x;  // 128 threads
    float u = 0.f, v = 0.f;
    for (int k = 0; k < 128; k++) {
        u += W_emb[k] * W1[k * 128 + f];
        v += b_emb[k] * W1[k * 128 + f];
    }
    su[f] = u; sv[f] = v;
    consts[f] = u; consts[128 + f] = v;
    __syncthreads();
    if (f < 4) {
        float P = 0.f, Q = 0.f, R = 0.f, S = 0.f;
        for (int j = 0; j < 32; j++) {
            float uu = su[f * 32 + j], vv = sv[f * 32 + j];
            float a = as1[f * 32 + j], d = ad1[f * 32 + j];
            P += uu * a; Q += vv * a; R += uu * d; S += vv * d;
        }
        consts[256 + f] = P; consts[260 + f] = Q; consts[264 + f] = R; consts[268 + f] = S;
    }
}

// Layer 1 aggregation: per-node scalars. S_out[n,h] = sum_e w_e * x[src_e], Sw[n,h] = sum_e w_e.
// 2 edge passes: max, then fused (denom + accumulate), normalize at end.
__global__ void k_agg1(const float* __restrict__ x, const int* __restrict__ row_ptr,
                       const int* __restrict__ csr_src, const float* __restrict__ consts,
                       float* __restrict__ S_out, float* __restrict__ Sw_out, int n) {
    int node = blockIdx.x * blockDim.x + threadIdx.x;
    if (node >= n) return;
    float P[4], Q[4], R[4], Sc[4];
#pragma unroll
    for (int h = 0; h < 4; h++) {
        P[h] = consts[256 + h]; Q[h] = consts[260 + h];
        R[h] = consts[264 + h]; Sc[h] = consts[268 + h];
    }
    float xd = x[node];
    float adv[4];
#pragma unroll
    for (int h = 0; h < 4; h++) adv[h] = xd * R[h] + Sc[h];
    int s0 = row_ptr[node], s1 = row_ptr[node + 1];

    float m[4] = {-INFINITY, -INFINITY, -INFINITY, -INFINITY};
    for (int i = s0; i < s1; i++) {
        float xs = x[csr_src[i]];
#pragma unroll
        for (int h = 0; h < 4; h++) {
            float e = LEAKY(xs * P[h] + Q[h] + adv[h]);
            m[h] = fmaxf(m[h], e);
        }
    }
    float den[4] = {0.f, 0.f, 0.f, 0.f};
    float S[4] = {0.f, 0.f, 0.f, 0.f};
    for (int i = s0; i < s1; i++) {
        float xs = x[csr_src[i]];
#pragma unroll
        for (int h = 0; h < 4; h++) {
            float e = LEAKY(xs * P[h] + Q[h] + adv[h]);
            float w = expf(e - m[h]);
            den[h] += w;
            S[h] += w * xs;
        }
    }
#pragma unroll
    for (int h = 0; h < 4; h++) {
        float inv = 1.f / (den[h] + 1e-16f);
        S_out[node * 4 + h] = S[h] * inv;
        Sw_out[node * 4 + h] = den[h] * inv;   // == 1 - eps-correction, keep exact form
    }
}

// h1[n,f] = relu(S[n,h(f)]*u[f] + Sw[n,h(f)]*v[f] + b1[f])
__global__ void k_h1(const float* __restrict__ S_out, const float* __restrict__ Sw,
                     const float* __restrict__ consts, const float* __restrict__ b1,
                     float* __restrict__ h, int n) {
    int idx = blockIdx.x * blockDim.x + threadIdx.x;
    if (idx >= n * 128) return;
    int node = idx >> 7, f = idx & 127;
    float val = S_out[node * 4 + (f >> 5)] * consts[f] +
                Sw[node * 4 + (f >> 5)] * consts[128 + f] + b1[f];
    h[idx] = fmaxf(val, 0.f);
}

// ---------------- GEMM: xp = h @ W (+ alpha epilogue), layers 2-4 ----------------
// 128x128 tile per block (256 threads), 8x8 per thread, K staged in 32-chunks.
__global__ __launch_bounds__(256) void k_gemm(const float* __restrict__ h, const float* __restrict__ W,
                                              const float* __restrict__ avs, const float* __restrict__ avd,
                                              float* __restrict__ xp, float* __restrict__ alpha_s,
                                              float* __restrict__ alpha_d, int n) {
    __shared__ float hT[32][132];  // [k][r]
    __shared__ float Wl[32][132];  // [k][c]
    int tid = threadIdx.x;
    int tx = tid & 15, ty = tid >> 4;
    int rb = blockIdx.x * 128;
    float acc[8][8];
#pragma unroll
    for (int r = 0; r < 8; r++)
#pragma unroll
        for (int c = 0; c < 8; c++) acc[r][c] = 0.f;

    for (int k0 = 0; k0 < 128; k0 += 32) {
        __syncthreads();
        int kq = (tid & 7) * 4;
#pragma unroll
        for (int s = 0; s < 4; s++) {
            int r = (tid >> 3) + (s << 5);
            int gr = rb + r;
            float4 hv = (gr < n) ? *(const float4*)(h + (size_t)gr * 128 + k0 + kq)
                                 : make_float4(0.f, 0.f, 0.f, 0.f);
            hT[kq + 0][r] = hv.x; hT[kq + 1][r] = hv.y;
            hT[kq + 2][r] = hv.z; hT[kq + 3][r] = hv.w;
        }
#pragma unroll
        for (int s = 0; s < 4; s++) {
            int f4 = tid + (s << 8);
            int k = f4 >> 5, c4 = (f4 & 31) * 4;
            *(float4*)(&Wl[k][c4]) = *(const float4*)(W + (k0 + k) * 128 + c4);
        }
        __syncthreads();
#pragma unroll
        for (int k = 0; k < 32; k++) {
            float4 t0 = *(const float4*)(&hT[k][ty * 8]);
            float4 t1 = *(const float4*)(&hT[k][ty * 8 + 4]);
            float4 w0 = *(const float4*)(&Wl[k][tx * 4]);
            float4 w1 = *(const float4*)(&Wl[k][tx * 4 + 64]);
            float a[8] = {t0.x, t0.y, t0.z, t0.w, t1.x, t1.y, t1.z, t1.w};
            float b[8] = {w0.x, w0.y, w0.z, w0.w, w1.x, w1.y, w1.z, w1.w};
#pragma unroll
            for (int r = 0; r < 8; r++)
#pragma unroll
                for (int c = 0; c < 8; c++) acc[r][c] += a[r] * b[c];
        }
    }

#pragma unroll
    for (int r = 0; r < 8; r++) {
        int gr = rb + ty * 8 + r;
        if (gr < n) {
            float4 o0 = make_float4(acc[r][0], acc[r][1], acc[r][2], acc[r][3]);
            float4 o1 = make_float4(acc[r][4], acc[r][5], acc[r][6], acc[r][7]);
            *(float4*)(xp + (size_t)gr * 128 + tx * 4) = o0;
            *(float4*)(xp + (size_t)gr * 128 + tx * 4 + 64) = o1;
        }
    }
    float asv[8], adv[8];
#pragma unroll
    for (int j = 0; j < 4; j++) {
        asv[j] = avs[tx * 4 + j];       asv[4 + j] = avs[tx * 4 + 64 + j];
        adv[j] = avd[tx * 4 + j];       adv[4 + j] = avd[tx * 4 + 64 + j];
    }
#pragma unroll
    for (int r = 0; r < 8; r++) {
        float ps = 0.f, pd = 0.f;
#pragma unroll
        for (int c = 0; c < 8; c++) { ps += acc[r][c] * asv[c]; pd += acc[r][c] * adv[c]; }
#pragma unroll
        for (int off = 1; off < 16; off <<= 1) {
            ps += __shfl_xor(ps, off, 16);
            pd += __shfl_xor(pd, off, 16);
        }
        int gr = rb + ty * 8 + r;
        if (tx == 0 && gr < n) { alpha_s[gr] = ps; alpha_d[gr] = pd; }
    }
}

// ---------------- Aggregation, layers 2-4: one wave per dst node ----------------
// 2 edge passes: max, then fused (denom + message accumulate); normalize once.
__global__ __launch_bounds__(256) void k_agg(const float* __restrict__ xp, const float* __restrict__ as,
                                             const float* __restrict__ ad, const int* __restrict__ row_ptr,
                                             const int* __restrict__ csr_src, const float* __restrict__ bias,
                                             float* __restrict__ out, int n, int do_relu) {
    int w = threadIdx.x >> 6, lane = threadIdx.x & 63;
    int node = blockIdx.x * 4 + w;
    if (node >= n) return;
    int s0 = row_ptr[node], s1 = row_ptr[node + 1];
    float adval = ad[node];

    // pass A: max (lane-parallel over edges)
    float m = -INFINITY;
    for (int i = s0 + lane; i < s1; i += 64) {
        float e = LEAKY(as[csr_src[i]] + adval);
        m = fmaxf(m, e);
    }
#pragma unroll
    for (int off = 32; off > 0; off >>= 1) m = fmaxf(m, __shfl_xor(m, off, 64));

    // pass B: fused denom + accumulate; lane -> feature pair (f = 2*lane)
    float den = 0.f;
    float2 accv = make_float2(0.f, 0.f);
    const float2* xp2 = (const float2*)xp;
    for (int i = s0; i < s1; i++) {
        int src = csr_src[i];
        float e = LEAKY(as[src] + adval);
        float wt = expf(e - m);
        den += wt;
        float2 v = xp2[(size_t)src * 64 + lane];
        accv.x += wt * v.x;
        accv.y += wt * v.y;
    }
    float inv = 1.f / (den + 1e-16f);
    float2 b = ((const float2*)bias)[lane];
    float o0 = accv.x * inv + b.x, o1 = accv.y * inv + b.y;
    if (do_relu) { o0 = fmaxf(o0, 0.f); o1 = fmaxf(o1, 0.f); }
    ((float2*)out)[(size_t)node * 64 + lane] = make_float2(o0, o1);
}

// ---------------- launch ----------------

extern "C" void kernel_launch(void* const* d_in, const int* in_sizes, int n_in,
                              void* d_out, int out_size, void* d_ws, size_t ws_size,
                              hipStream_t stream) {
    const float* x     = (const float*)d_in[0];
    const int*   ei    = (const int*)d_in[1];
    const float* W_emb = (const float*)d_in[2];
    const float* b_emb = (const float*)d_in[3];
    const float* W1    = (const float*)d_in[4];
    const float* as1   = (const float*)d_in[5];
    const float* ad1   = (const float*)d_in[6];
    const float* b1    = (const float*)d_in[7];
    const float* Wl[3]  = {(const float*)d_in[8],  (const float*)d_in[12], (const float*)d_in[16]};
    const float* asl[3] = {(const float*)d_in[9],  (const float*)d_in[13], (const float*)d_in[17]};
    const float* adl[3] = {(const float*)d_in[10], (const float*)d_in[14], (const float*)d_in[18]};
    const float* bl[3]  = {(const float*)d_in[11], (const float*)d_in[15], (const float*)d_in[19]};
    float* out = (float*)d_out;

    int N = in_sizes[0];
    int E = in_sizes[1] / 2;
    int Et = E + N;
    int nb = (N + SCAN_BLK - 1) / SCAN_BLK;

    char* ws = (char*)d_ws;
    size_t off = 0;
    auto alloc = [&](size_t bytes) { size_t p = off; off += (bytes + 255) & ~(size_t)255; return p; };
    int*   deg      = (int*)(ws + alloc((size_t)N * 4));
    int*   row_ptr  = (int*)(ws + alloc((size_t)(N + 1) * 4));
    int*   cursor   = (int*)(ws + alloc((size_t)N * 4));
    int*   csr_src  = (int*)(ws + alloc((size_t)Et * 4));
    int*   scantmp  = (int*)(ws + alloc((size_t)N * 4));
    int*   blocksum = (int*)(ws + alloc((size_t)nb * 4));
    int*   blockoff = (int*)(ws + alloc((size_t)nb * 4));
    float* consts   = (float*)(ws + alloc(272 * 4));
    float* S_out    = (float*)(ws + alloc((size_t)N * 4 * 4));
    float* Sw       = (float*)(ws + alloc((size_t)N * 4 * 4));
    float* alpha_s  = (float*)(ws + alloc((size_t)N * 4));
    float* alpha_d  = (float*)(ws + alloc((size_t)N * 4));
    float* hbuf     = (float*)(ws + alloc((size_t)N * 128 * 4));
    float* xp       = (float*)(ws + alloc((size_t)N * 128 * 4));

    hipMemsetAsync(deg, 0, (size_t)N * 4, stream);
    k_hist<<<(Et + 255) / 256, 256, 0, stream>>>(ei, E, N, deg);
    k_scan1<<<nb, SCAN_BLK, 0, stream>>>(deg, scantmp, blocksum, N);
    k_scan2<<<1, 256, 0, stream>>>(blocksum, blockoff, nb, row_ptr, N);
    k_scan3<<<(N + 255) / 256, 256, 0, stream>>>(scantmp, blockoff, row_ptr, cursor, N);
    k_scatter<<<(Et + 255) / 256, 256, 0, stream>>>(ei, E, N, cursor, csr_src);

    k_emb<<<1, 128, 0, stream>>>(W_emb, b_emb, W1, as1, ad1, consts);
    k_agg1<<<(N + 255) / 256, 256, 0, stream>>>(x, row_ptr, csr_src, consts, S_out, Sw, N);
    k_h1<<<((size_t)N * 128 + 255) / 256, 256, 0, stream>>>(S_out, Sw, consts, b1, hbuf, N);

    for (int l = 0; l < 3; l++) {
        k_gemm<<<(N + 127) / 128, 256, 0, stream>>>(hbuf, Wl[l], asl[l], adl[l],
                                                    xp, alpha_s, alpha_d, N);
        float* dst = (l == 2) ? out : hbuf;
        k_agg<<<(N + 3) / 4, 256, 0, stream>>>(xp, alpha_s, alpha_d, row_ptr, csr_src,
                                               bl[l], dst, N, (l < 2) ? 1 : 0);
    }
}

// Round 3
// 368.108 us; speedup vs baseline: 1.5179x; 1.2331x over previous
//
#include <hip/hip_runtime.h>
#include <math.h>

// GAT model: N=50000 nodes, E=500000 edges (+N self loops), D=128, layer1 heads=4.
// All f32. CSR-by-dst built on device once per launch (graph shared by all layers).

#define LEAKY(e) ((e) > 0.f ? (e) : 0.2f * (e))
#define SCAN_BLK 1024

// ---------------- CSR construction ----------------

__global__ void k_hist(const int* __restrict__ ei, int E, int N, int* __restrict__ deg) {
    int e = blockIdx.x * blockDim.x + threadIdx.x;
    int Et = E + N;
    if (e >= Et) return;
    int dst = (e < E) ? ei[2 * e + 1] : (e - E);
    atomicAdd(&deg[dst], 1);
}

// phase 1: per-block inclusive scan; write exclusive-within-block + block sums
__global__ __launch_bounds__(SCAN_BLK) void k_scan1(const int* __restrict__ deg,
                                                    int* __restrict__ tmp,
                                                    int* __restrict__ blocksum, int n) {
    __shared__ int buf[SCAN_BLK];
    int tid = threadIdx.x;
    int gid = blockIdx.x * SCAN_BLK + tid;
    int v = (gid < n) ? deg[gid] : 0;
    buf[tid] = v;
    __syncthreads();
#pragma unroll
    for (int off = 1; off < SCAN_BLK; off <<= 1) {
        int t = (tid >= off) ? buf[tid - off] : 0;
        __syncthreads();
        buf[tid] += t;
        __syncthreads();
    }
    if (gid < n) tmp[gid] = buf[tid] - v;
    if (tid == SCAN_BLK - 1) blocksum[blockIdx.x] = buf[tid];
}

// phase 2: scan the (<=256) block sums in one block
__global__ __launch_bounds__(256) void k_scan2(const int* __restrict__ blocksum,
                                               int* __restrict__ blockoff, int nb,
                                               int* __restrict__ row_ptr, int n) {
    __shared__ int buf[256];
    int tid = threadIdx.x;
    int v = (tid < nb) ? blocksum[tid] : 0;
    buf[tid] = v;
    __syncthreads();
#pragma unroll
    for (int off = 1; off < 256; off <<= 1) {
        int t = (tid >= off) ? buf[tid - off] : 0;
        __syncthreads();
        buf[tid] += t;
        __syncthreads();
    }
    if (tid < nb) blockoff[tid] = buf[tid] - v;
    if (tid == 255) row_ptr[n] = buf[tid];
}

// phase 3: add block offsets
__global__ void k_scan3(const int* __restrict__ tmp, const int* __restrict__ blockoff,
                        int* __restrict__ row_ptr, int* __restrict__ cursor, int n) {
    int gid = blockIdx.x * blockDim.x + threadIdx.x;
    if (gid >= n) return;
    int v = tmp[gid] + blockoff[gid / SCAN_BLK];
    row_ptr[gid] = v;
    cursor[gid] = v;
}

__global__ void k_scatter(const int* __restrict__ ei, int E, int N,
                          int* __restrict__ cursor, int* __restrict__ csr_src) {
    int e = blockIdx.x * blockDim.x + threadIdx.x;
    int Et = E + N;
    if (e >= Et) return;
    int src, dst;
    if (e < E) { src = ei[2 * e]; dst = ei[2 * e + 1]; }
    else { src = dst = e - E; }
    int pos = atomicAdd(&cursor[dst], 1);
    csr_src[pos] = src;
}

// ---------------- Layer-1 rank-1 constants ----------------
// consts layout (floats): u[128] @0, v[128] @128, P[4]@256, Q[4]@260, R[4]@264, S[4]@268

__global__ void k_emb(const float* __restrict__ W_emb, const float* __restrict__ b_emb,
                      const float* __restrict__ W1, const float* __restrict__ as1,
                      const float* __restrict__ ad1, float* __restrict__ consts) {
    __shared__ float su[128], sv[128];
    int f = threadIdx.x;  // 128 threads
    float u = 0.f, v = 0.f;
    for (int k = 0; k < 128; k++) {
        u += W_emb[k] * W1[k * 128 + f];
        v += b_emb[k] * W1[k * 128 + f];
    }
    su[f] = u; sv[f] = v;
    consts[f] = u; consts[128 + f] = v;
    __syncthreads();
    if (f < 4) {
        float P = 0.f, Q = 0.f, R = 0.f, S = 0.f;
        for (int j = 0; j < 32; j++) {
            float uu = su[f * 32 + j], vv = sv[f * 32 + j];
            float a = as1[f * 32 + j], d = ad1[f * 32 + j];
            P += uu * a; Q += vv * a; R += uu * d; S += vv * d;
        }
        consts[256 + f] = P; consts[260 + f] = Q; consts[264 + f] = R; consts[268 + f] = S;
    }
}

// Layer 1 aggregation: per-node scalars. S_out[n,h] = sum_e w_e * x[src_e], Sw[n,h] = sum_e w_e.
__global__ void k_agg1(const float* __restrict__ x, const int* __restrict__ row_ptr,
                       const int* __restrict__ csr_src, const float* __restrict__ consts,
                       float* __restrict__ S_out, float* __restrict__ Sw_out, int n) {
    int node = blockIdx.x * blockDim.x + threadIdx.x;
    if (node >= n) return;
    float P[4], Q[4], R[4], Sc[4];
#pragma unroll
    for (int h = 0; h < 4; h++) {
        P[h] = consts[256 + h]; Q[h] = consts[260 + h];
        R[h] = consts[264 + h]; Sc[h] = consts[268 + h];
    }
    float xd = x[node];
    float adv[4];
#pragma unroll
    for (int h = 0; h < 4; h++) adv[h] = xd * R[h] + Sc[h];
    int s0 = row_ptr[node], s1 = row_ptr[node + 1];

    float m[4] = {-INFINITY, -INFINITY, -INFINITY, -INFINITY};
    for (int i = s0; i < s1; i++) {
        float xs = x[csr_src[i]];
#pragma unroll
        for (int h = 0; h < 4; h++) {
            float e = LEAKY(xs * P[h] + Q[h] + adv[h]);
            m[h] = fmaxf(m[h], e);
        }
    }
    float den[4] = {0.f, 0.f, 0.f, 0.f};
    float S[4] = {0.f, 0.f, 0.f, 0.f};
    for (int i = s0; i < s1; i++) {
        float xs = x[csr_src[i]];
#pragma unroll
        for (int h = 0; h < 4; h++) {
            float e = LEAKY(xs * P[h] + Q[h] + adv[h]);
            float w = __expf(e - m[h]);
            den[h] += w;
            S[h] += w * xs;
        }
    }
#pragma unroll
    for (int h = 0; h < 4; h++) {
        float inv = 1.f / (den[h] + 1e-16f);
        S_out[node * 4 + h] = S[h] * inv;
        Sw_out[node * 4 + h] = den[h] * inv;
    }
}

// h1[n,f] = relu(S[n,h(f)]*u[f] + Sw[n,h(f)]*v[f] + b1[f])
__global__ void k_h1(const float* __restrict__ S_out, const float* __restrict__ Sw,
                     const float* __restrict__ consts, const float* __restrict__ b1,
                     float* __restrict__ h, int n) {
    int idx = blockIdx.x * blockDim.x + threadIdx.x;
    if (idx >= n * 128) return;
    int node = idx >> 7, f = idx & 127;
    float val = S_out[node * 4 + (f >> 5)] * consts[f] +
                Sw[node * 4 + (f >> 5)] * consts[128 + f] + b1[f];
    h[idx] = fmaxf(val, 0.f);
}

// ---------------- GEMM: xp = h @ W (+ alpha epilogue), layers 2-4 ----------------
__global__ __launch_bounds__(256) void k_gemm(const float* __restrict__ h, const float* __restrict__ W,
                                              const float* __restrict__ avs, const float* __restrict__ avd,
                                              float* __restrict__ xp, float* __restrict__ alpha_s,
                                              float* __restrict__ alpha_d, int n) {
    __shared__ float hT[32][132];  // [k][r]
    __shared__ float Wl[32][132];  // [k][c]
    int tid = threadIdx.x;
    int tx = tid & 15, ty = tid >> 4;
    int rb = blockIdx.x * 128;
    float acc[8][8];
#pragma unroll
    for (int r = 0; r < 8; r++)
#pragma unroll
        for (int c = 0; c < 8; c++) acc[r][c] = 0.f;

    for (int k0 = 0; k0 < 128; k0 += 32) {
        __syncthreads();
        int kq = (tid & 7) * 4;
#pragma unroll
        for (int s = 0; s < 4; s++) {
            int r = (tid >> 3) + (s << 5);
            int gr = rb + r;
            float4 hv = (gr < n) ? *(const float4*)(h + (size_t)gr * 128 + k0 + kq)
                                 : make_float4(0.f, 0.f, 0.f, 0.f);
            hT[kq + 0][r] = hv.x; hT[kq + 1][r] = hv.y;
            hT[kq + 2][r] = hv.z; hT[kq + 3][r] = hv.w;
        }
#pragma unroll
        for (int s = 0; s < 4; s++) {
            int f4 = tid + (s << 8);
            int k = f4 >> 5, c4 = (f4 & 31) * 4;
            *(float4*)(&Wl[k][c4]) = *(const float4*)(W + (k0 + k) * 128 + c4);
        }
        __syncthreads();
#pragma unroll
        for (int k = 0; k < 32; k++) {
            float4 t0 = *(const float4*)(&hT[k][ty * 8]);
            float4 t1 = *(const float4*)(&hT[k][ty * 8 + 4]);
            float4 w0 = *(const float4*)(&Wl[k][tx * 4]);
            float4 w1 = *(const float4*)(&Wl[k][tx * 4 + 64]);
            float a[8] = {t0.x, t0.y, t0.z, t0.w, t1.x, t1.y, t1.z, t1.w};
            float b[8] = {w0.x, w0.y, w0.z, w0.w, w1.x, w1.y, w1.z, w1.w};
#pragma unroll
            for (int r = 0; r < 8; r++)
#pragma unroll
                for (int c = 0; c < 8; c++) acc[r][c] += a[r] * b[c];
        }
    }

#pragma unroll
    for (int r = 0; r < 8; r++) {
        int gr = rb + ty * 8 + r;
        if (gr < n) {
            float4 o0 = make_float4(acc[r][0], acc[r][1], acc[r][2], acc[r][3]);
            float4 o1 = make_float4(acc[r][4], acc[r][5], acc[r][6], acc[r][7]);
            *(float4*)(xp + (size_t)gr * 128 + tx * 4) = o0;
            *(float4*)(xp + (size_t)gr * 128 + tx * 4 + 64) = o1;
        }
    }
    float asv[8], adv[8];
#pragma unroll
    for (int j = 0; j < 4; j++) {
        asv[j] = avs[tx * 4 + j];       asv[4 + j] = avs[tx * 4 + 64 + j];
        adv[j] = avd[tx * 4 + j];       adv[4 + j] = avd[tx * 4 + 64 + j];
    }
#pragma unroll
    for (int r = 0; r < 8; r++) {
        float ps = 0.f, pd = 0.f;
#pragma unroll
        for (int c = 0; c < 8; c++) { ps += acc[r][c] * asv[c]; pd += acc[r][c] * adv[c]; }
#pragma unroll
        for (int off = 1; off < 16; off <<= 1) {
            ps += __shfl_xor(ps, off, 16);
            pd += __shfl_xor(pd, off, 16);
        }
        int gr = rb + ty * 8 + r;
        if (tx == 0 && gr < n) { alpha_s[gr] = ps; alpha_d[gr] = pd; }
    }
}

// ---------------- Aggregation, layers 2-4: one wave per dst node ----------------
// Fast path (deg<=64): lane i owns edge i; weight computed ONCE per edge, packed
// (src,wt) staged in wave-private LDS; gather pass reads broadcast ds_read_b64.
__global__ __launch_bounds__(256) void k_agg(const float* __restrict__ xp, const float* __restrict__ as,
                                             const float* __restrict__ ad, const int* __restrict__ row_ptr,
                                             const int* __restrict__ csr_src, const float* __restrict__ bias,
                                             float* __restrict__ out, int n, int do_relu) {
    __shared__ float2 s_sw[4][64];  // .x = src (bit-cast), .y = weight
    int w = threadIdx.x >> 6, lane = threadIdx.x & 63;
    int node = blockIdx.x * 4 + w;
    if (node >= n) return;
    int s0 = row_ptr[node], s1 = row_ptr[node + 1];
    int deg = s1 - s0;
    float adval = ad[node];
    const float2* xp2 = (const float2*)xp;
    float2 accv = make_float2(0.f, 0.f);
    float den;

    if (deg <= 64) {
        // lane i owns edge i
        int src = 0;
        float e = -INFINITY;
        if (lane < deg) {
            src = csr_src[s0 + lane];
            float v = as[src] + adval;
            e = LEAKY(v);
        }
        float m = e;
#pragma unroll
        for (int off = 32; off > 0; off >>= 1) m = fmaxf(m, __shfl_xor(m, off, 64));
        float wt = (lane < deg) ? __expf(e - m) : 0.f;
        den = wt;
#pragma unroll
        for (int off = 32; off > 0; off >>= 1) den += __shfl_xor(den, off, 64);
        s_sw[w][lane] = make_float2(__int_as_float(src), wt);
        __builtin_amdgcn_wave_barrier();

        // gather pass, unrolled x4 for MLP
        int j = 0;
        for (; j + 4 <= deg; j += 4) {
            float2 p0 = s_sw[w][j + 0];
            float2 p1 = s_sw[w][j + 1];
            float2 p2 = s_sw[w][j + 2];
            float2 p3 = s_sw[w][j + 3];
            float2 v0 = xp2[(size_t)__float_as_int(p0.x) * 64 + lane];
            float2 v1 = xp2[(size_t)__float_as_int(p1.x) * 64 + lane];
            float2 v2 = xp2[(size_t)__float_as_int(p2.x) * 64 + lane];
            float2 v3 = xp2[(size_t)__float_as_int(p3.x) * 64 + lane];
            accv.x += p0.y * v0.x; accv.y += p0.y * v0.y;
            accv.x += p1.y * v1.x; accv.y += p1.y * v1.y;
            accv.x += p2.y * v2.x; accv.y += p2.y * v2.y;
            accv.x += p3.y * v3.x; accv.y += p3.y * v3.y;
        }
        for (; j < deg; j++) {
            float2 p = s_sw[w][j];
            float2 v = xp2[(size_t)__float_as_int(p.x) * 64 + lane];
            accv.x += p.y * v.x; accv.y += p.y * v.y;
        }
    } else {
        // generic fallback (recompute path); not expected on this graph
        float m = -INFINITY;
        for (int i = s0 + lane; i < s1; i += 64) {
            float e = LEAKY(as[csr_src[i]] + adval);
            m = fmaxf(m, e);
        }
#pragma unroll
        for (int off = 32; off > 0; off >>= 1) m = fmaxf(m, __shfl_xor(m, off, 64));
        den = 0.f;
        for (int i = s0; i < s1; i++) {
            int src = csr_src[i];
            float e = LEAKY(as[src] + adval);
            float wt = __expf(e - m);
            den += wt;
            float2 v = xp2[(size_t)src * 64 + lane];
            accv.x += wt * v.x;
            accv.y += wt * v.y;
        }
    }

    float inv = 1.f / (den + 1e-16f);
    float2 b = ((const float2*)bias)[lane];
    float o0 = accv.x * inv + b.x, o1 = accv.y * inv + b.y;
    if (do_relu) { o0 = fmaxf(o0, 0.f); o1 = fmaxf(o1, 0.f); }
    ((float2*)out)[(size_t)node * 64 + lane] = make_float2(o0, o1);
}

// ---------------- launch ----------------

extern "C" void kernel_launch(void* const* d_in, const int* in_sizes, int n_in,
                              void* d_out, int out_size, void* d_ws, size_t ws_size,
                              hipStream_t stream) {
    const float* x     = (const float*)d_in[0];
    const int*   ei    = (const int*)d_in[1];
    const float* W_emb = (const float*)d_in[2];
    const float* b_emb = (const float*)d_in[3];
    const float* W1    = (const float*)d_in[4];
    const float* as1   = (const float*)d_in[5];
    const float* ad1   = (const float*)d_in[6];
    const float* b1    = (const float*)d_in[7];
    const float* Wl[3]  = {(const float*)d_in[8],  (const float*)d_in[12], (const float*)d_in[16]};
    const float* asl[3] = {(const float*)d_in[9],  (const float*)d_in[13], (const float*)d_in[17]};
    const float* adl[3] = {(const float*)d_in[10], (const float*)d_in[14], (const float*)d_in[18]};
    const float* bl[3]  = {(const float*)d_in[11], (const float*)d_in[15], (const float*)d_in[19]};
    float* out = (float*)d_out;

    int N = in_sizes[0];
    int E = in_sizes[1] / 2;
    int Et = E + N;
    int nb = (N + SCAN_BLK - 1) / SCAN_BLK;

    char* ws = (char*)d_ws;
    size_t off = 0;
    auto alloc = [&](size_t bytes) { size_t p = off; off += (bytes + 255) & ~(size_t)255; return p; };
    int*   deg      = (int*)(ws + alloc((size_t)N * 4));
    int*   row_ptr  = (int*)(ws + alloc((size_t)(N + 1) * 4));
    int*   cursor   = (int*)(ws + alloc((size_t)N * 4));
    int*   csr_src  = (int*)(ws + alloc((size_t)Et * 4));
    int*   scantmp  = (int*)(ws + alloc((size_t)N * 4));
    int*   blocksum = (int*)(ws + alloc((size_t)nb * 4));
    int*   blockoff = (int*)(ws + alloc((size_t)nb * 4));
    float* consts   = (float*)(ws + alloc(272 * 4));
    float* S_out    = (float*)(ws + alloc((size_t)N * 4 * 4));
    float* Sw       = (float*)(ws + alloc((size_t)N * 4 * 4));
    float* alpha_s  = (float*)(ws + alloc((size_t)N * 4));
    float* alpha_d  = (float*)(ws + alloc((size_t)N * 4));
    float* hbuf     = (float*)(ws + alloc((size_t)N * 128 * 4));
    float* xp       = (float*)(ws + alloc((size_t)N * 128 * 4));

    hipMemsetAsync(deg, 0, (size_t)N * 4, stream);
    k_hist<<<(Et + 255) / 256, 256, 0, stream>>>(ei, E, N, deg);
    k_scan1<<<nb, SCAN_BLK, 0, stream>>>(deg, scantmp, blocksum, N);
    k_scan2<<<1, 256, 0, stream>>>(blocksum, blockoff, nb, row_ptr, N);
    k_scan3<<<(N + 255) / 256, 256, 0, stream>>>(scantmp, blockoff, row_ptr, cursor, N);
    k_scatter<<<(Et + 255) / 256, 256, 0, stream>>>(ei, E, N, cursor, csr_src);

    k_emb<<<1, 128, 0, stream>>>(W_emb, b_emb, W1, as1, ad1, consts);
    k_agg1<<<(N + 255) / 256, 256, 0, stream>>>(x, row_ptr, csr_src, consts, S_out, Sw, N);
    k_h1<<<((size_t)N * 128 + 255) / 256, 256, 0, stream>>>(S_out, Sw, consts, b1, hbuf, N);

    for (int l = 0; l < 3; l++) {
        k_gemm<<<(N + 127) / 128, 256, 0, stream>>>(hbuf, Wl[l], asl[l], adl[l],
                                                    xp, alpha_s, alpha_d, N);
        float* dst = (l == 2) ? out : hbuf;
        k_agg<<<(N + 3) / 4, 256, 0, stream>>>(xp, alpha_s, alpha_d, row_ptr, csr_src,
                                               bl[l], dst, N, (l < 2) ? 1 : 0);
    }
}

// Round 4
// 322.364 us; speedup vs baseline: 1.7333x; 1.1419x over previous
//
#include <hip/hip_runtime.h>
#include <math.h>

// GAT model: N=50000 nodes, E=500000 edges (+N self loops), D=128, layer1 heads=4.
// CSR-by-dst built on device; layers 2-4 GEMMs use MFMA bf16x3 (hi/lo split).

#define LEAKY(e) ((e) > 0.f ? (e) : 0.2f * (e))
#define SCAN_BLK 1024

typedef __attribute__((ext_vector_type(8))) short bf16x8;
typedef __attribute__((ext_vector_type(4))) float f32x4;

__device__ inline ushort f32_to_bf16_rne(float f) {
    unsigned u = __float_as_uint(f);
    unsigned r = (u + 0x7FFFu + ((u >> 16) & 1u)) >> 16;
    return (ushort)r;
}
__device__ inline float bf16_to_f32(ushort h) { return __uint_as_float((unsigned)h << 16); }
__device__ inline unsigned pack_bf16_pair(float a, float b) {
    return (unsigned)f32_to_bf16_rne(a) | ((unsigned)f32_to_bf16_rne(b) << 16);
}

// ---------------- CSR construction ----------------

__global__ void k_hist(const int* __restrict__ ei, int E, int N, int* __restrict__ deg) {
    int e = blockIdx.x * blockDim.x + threadIdx.x;
    int Et = E + N;
    if (e >= Et) return;
    int dst = (e < E) ? ei[2 * e + 1] : (e - E);
    atomicAdd(&deg[dst], 1);
}

__global__ __launch_bounds__(SCAN_BLK) void k_scan1(const int* __restrict__ deg,
                                                    int* __restrict__ tmp,
                                                    int* __restrict__ blocksum, int n) {
    __shared__ int buf[SCAN_BLK];
    int tid = threadIdx.x;
    int gid = blockIdx.x * SCAN_BLK + tid;
    int v = (gid < n) ? deg[gid] : 0;
    buf[tid] = v;
    __syncthreads();
#pragma unroll
    for (int off = 1; off < SCAN_BLK; off <<= 1) {
        int t = (tid >= off) ? buf[tid - off] : 0;
        __syncthreads();
        buf[tid] += t;
        __syncthreads();
    }
    if (gid < n) tmp[gid] = buf[tid] - v;
    if (tid == SCAN_BLK - 1) blocksum[blockIdx.x] = buf[tid];
}

__global__ __launch_bounds__(256) void k_scan2(const int* __restrict__ blocksum,
                                               int* __restrict__ blockoff, int nb,
                                               int* __restrict__ row_ptr, int n) {
    __shared__ int buf[256];
    int tid = threadIdx.x;
    int v = (tid < nb) ? blocksum[tid] : 0;
    buf[tid] = v;
    __syncthreads();
#pragma unroll
    for (int off = 1; off < 256; off <<= 1) {
        int t = (tid >= off) ? buf[tid - off] : 0;
        __syncthreads();
        buf[tid] += t;
        __syncthreads();
    }
    if (tid < nb) blockoff[tid] = buf[tid] - v;
    if (tid == 255) row_ptr[n] = buf[tid];
}

__global__ void k_scan3(const int* __restrict__ tmp, const int* __restrict__ blockoff,
                        int* __restrict__ row_ptr, int* __restrict__ cursor, int n) {
    int gid = blockIdx.x * blockDim.x + threadIdx.x;
    if (gid >= n) return;
    int v = tmp[gid] + blockoff[gid / SCAN_BLK];
    row_ptr[gid] = v;
    cursor[gid] = v;
}

__global__ void k_scatter(const int* __restrict__ ei, int E, int N,
                          int* __restrict__ cursor, int* __restrict__ csr_src) {
    int e = blockIdx.x * blockDim.x + threadIdx.x;
    int Et = E + N;
    if (e >= Et) return;
    int src, dst;
    if (e < E) { src = ei[2 * e]; dst = ei[2 * e + 1]; }
    else { src = dst = e - E; }
    int pos = atomicAdd(&cursor[dst], 1);
    csr_src[pos] = src;
}

// ---------------- Weight prep: WT hi/lo (bf16, transposed) + was/wad ----------------

__global__ void k_wsplit(const float* __restrict__ W,
                         ushort* __restrict__ wt_hi, ushort* __restrict__ wt_lo) {
    int idx = blockIdx.x * blockDim.x + threadIdx.x;   // 0..16383
    if (idx >= 128 * 128) return;
    int k = idx >> 7, c = idx & 127;
    float w = W[idx];
    ushort hi = f32_to_bf16_rne(w);
    float hif = bf16_to_f32(hi);
    ushort lo = f32_to_bf16_rne(w - hif);
    wt_hi[c * 128 + k] = hi;
    wt_lo[c * 128 + k] = lo;
}

__global__ void k_wvec(const float* __restrict__ W, const float* __restrict__ as_v,
                       const float* __restrict__ ad_v,
                       float* __restrict__ was, float* __restrict__ wad) {
    int k = threadIdx.x;  // 128 threads
    float s = 0.f, d = 0.f;
    for (int c = 0; c < 128; c++) {
        float w = W[k * 128 + c];
        s += w * as_v[c];
        d += w * ad_v[c];
    }
    was[k] = s; wad[k] = d;
}

// ---------------- Layer-1 rank-1 constants ----------------
// consts layout (floats): u[128] @0, v[128] @128, P[4]@256, Q[4]@260, R[4]@264, S[4]@268

__global__ void k_emb(const float* __restrict__ W_emb, const float* __restrict__ b_emb,
                      const float* __restrict__ W1, const float* __restrict__ as1,
                      const float* __restrict__ ad1, float* __restrict__ consts) {
    __shared__ float su[128], sv[128];
    int f = threadIdx.x;  // 128 threads
    float u = 0.f, v = 0.f;
    for (int k = 0; k < 128; k++) {
        u += W_emb[k] * W1[k * 128 + f];
        v += b_emb[k] * W1[k * 128 + f];
    }
    su[f] = u; sv[f] = v;
    consts[f] = u; consts[128 + f] = v;
    __syncthreads();
    if (f < 4) {
        float P = 0.f, Q = 0.f, R = 0.f, S = 0.f;
        for (int j = 0; j < 32; j++) {
            float uu = su[f * 32 + j], vv = sv[f * 32 + j];
            float a = as1[f * 32 + j], d = ad1[f * 32 + j];
            P += uu * a; Q += vv * a; R += uu * d; S += vv * d;
        }
        consts[256 + f] = P; consts[260 + f] = Q; consts[264 + f] = R; consts[268 + f] = S;
    }
}

// Layer 1 aggregation: per-node scalars.
__global__ void k_agg1(const float* __restrict__ x, const int* __restrict__ row_ptr,
                       const int* __restrict__ csr_src, const float* __restrict__ consts,
                       float* __restrict__ S_out, float* __restrict__ Sw_out, int n) {
    int node = blockIdx.x * blockDim.x + threadIdx.x;
    if (node >= n) return;
    float P[4], Q[4], R[4], Sc[4];
#pragma unroll
    for (int h = 0; h < 4; h++) {
        P[h] = consts[256 + h]; Q[h] = consts[260 + h];
        R[h] = consts[264 + h]; Sc[h] = consts[268 + h];
    }
    float xd = x[node];
    float adv[4];
#pragma unroll
    for (int h = 0; h < 4; h++) adv[h] = xd * R[h] + Sc[h];
    int s0 = row_ptr[node], s1 = row_ptr[node + 1];

    float m[4] = {-INFINITY, -INFINITY, -INFINITY, -INFINITY};
    for (int i = s0; i < s1; i++) {
        float xs = x[csr_src[i]];
#pragma unroll
        for (int h = 0; h < 4; h++) {
            float e = LEAKY(xs * P[h] + Q[h] + adv[h]);
            m[h] = fmaxf(m[h], e);
        }
    }
    float den[4] = {0.f, 0.f, 0.f, 0.f};
    float S[4] = {0.f, 0.f, 0.f, 0.f};
    for (int i = s0; i < s1; i++) {
        float xs = x[csr_src[i]];
#pragma unroll
        for (int h = 0; h < 4; h++) {
            float e = LEAKY(xs * P[h] + Q[h] + adv[h]);
            float w = __expf(e - m[h]);
            den[h] += w;
            S[h] += w * xs;
        }
    }
#pragma unroll
    for (int h = 0; h < 4; h++) {
        float inv = 1.f / (den[h] + 1e-16f);
        S_out[node * 4 + h] = S[h] * inv;
        Sw_out[node * 4 + h] = den[h] * inv;
    }
}

// h1 producer: wave per node. Emits bf16 hi/lo of h1 + layer-2 alphas.
__global__ __launch_bounds__(256) void k_h1(const float* __restrict__ S_out, const float* __restrict__ Sw,
                                            const float* __restrict__ consts, const float* __restrict__ b1,
                                            const float* __restrict__ was2, const float* __restrict__ wad2,
                                            unsigned* __restrict__ h_hi, unsigned* __restrict__ h_lo,
                                            float* __restrict__ a_s, float* __restrict__ a_d, int n) {
    int w = threadIdx.x >> 6, lane = threadIdx.x & 63;
    int node = blockIdx.x * 4 + w;
    if (node >= n) return;
    int f0 = 2 * lane, f1 = f0 + 1;
    int h0 = f0 >> 5, h1i = f1 >> 5;
    float v0 = S_out[node * 4 + h0] * consts[f0] + Sw[node * 4 + h0] * consts[128 + f0] + b1[f0];
    float v1 = S_out[node * 4 + h1i] * consts[f1] + Sw[node * 4 + h1i] * consts[128 + f1] + b1[f1];
    v0 = fmaxf(v0, 0.f);
    v1 = fmaxf(v1, 0.f);
    // bf16 split
    ushort hi0 = f32_to_bf16_rne(v0), hi1 = f32_to_bf16_rne(v1);
    float r0 = v0 - bf16_to_f32(hi0), r1 = v1 - bf16_to_f32(hi1);
    h_hi[(size_t)node * 64 + lane] = (unsigned)hi0 | ((unsigned)hi1 << 16);
    h_lo[(size_t)node * 64 + lane] = pack_bf16_pair(r0, r1);
    // next-layer alphas
    float ps = v0 * was2[f0] + v1 * was2[f1];
    float pd = v0 * wad2[f0] + v1 * wad2[f1];
#pragma unroll
    for (int off = 32; off > 0; off >>= 1) {
        ps += __shfl_xor(ps, off, 64);
        pd += __shfl_xor(pd, off, 64);
    }
    if (lane == 0) { a_s[node] = ps; a_d[node] = pd; }
}

// ---------------- MFMA GEMM: xp = h @ W  (bf16x3, no LDS) ----------------
// Block: 256 thr = 4 waves in 2x2; wave tile 64x64; 16 MFMA tiles of 16x16, K=128.
__global__ __launch_bounds__(256) void k_gemm_mfma(const ushort* __restrict__ h_hi,
                                                   const ushort* __restrict__ h_lo,
                                                   const ushort* __restrict__ wt_hi,
                                                   const ushort* __restrict__ wt_lo,
                                                   float* __restrict__ xp, int n) {
    int tid = threadIdx.x;
    int wid = tid >> 6, lane = tid & 63;
    int wr = wid >> 1, wc = wid & 1;
    int row_base = blockIdx.x * 128 + wr * 64;
    int col_base = wc * 64;
    int lrow = lane & 15;
    int kgrp = lane >> 4;

    f32x4 acc[4][4];
#pragma unroll
    for (int m = 0; m < 4; m++)
#pragma unroll
        for (int nn = 0; nn < 4; nn++) {
            acc[m][nn][0] = 0.f; acc[m][nn][1] = 0.f;
            acc[m][nn][2] = 0.f; acc[m][nn][3] = 0.f;
        }

#pragma unroll
    for (int ks = 0; ks < 4; ks++) {
        int kbase = ks * 32 + kgrp * 8;
        bf16x8 ah[4], al[4], bh[4], bl[4];
#pragma unroll
        for (int m = 0; m < 4; m++) {
            int row = row_base + m * 16 + lrow;
            row = min(row, n - 1);
            size_t off = (size_t)row * 128 + kbase;
            ah[m] = *(const bf16x8*)(h_hi + off);
            al[m] = *(const bf16x8*)(h_lo + off);
        }
#pragma unroll
        for (int nn = 0; nn < 4; nn++) {
            int col = col_base + nn * 16 + lrow;
            size_t off = (size_t)col * 128 + kbase;
            bh[nn] = *(const bf16x8*)(wt_hi + off);
            bl[nn] = *(const bf16x8*)(wt_lo + off);
        }
#pragma unroll
        for (int m = 0; m < 4; m++)
#pragma unroll
            for (int nn = 0; nn < 4; nn++) {
                acc[m][nn] = __builtin_amdgcn_mfma_f32_16x16x32_bf16(ah[m], bh[nn], acc[m][nn], 0, 0, 0);
                acc[m][nn] = __builtin_amdgcn_mfma_f32_16x16x32_bf16(ah[m], bl[nn], acc[m][nn], 0, 0, 0);
                acc[m][nn] = __builtin_amdgcn_mfma_f32_16x16x32_bf16(al[m], bh[nn], acc[m][nn], 0, 0, 0);
            }
    }

    // store: tile (m,nn): row = row_base + m*16 + kgrp*4 + i, col = col_base + nn*16 + lrow
#pragma unroll
    for (int m = 0; m < 4; m++)
#pragma unroll
        for (int i = 0; i < 4; i++) {
            int row = row_base + m * 16 + kgrp * 4 + i;
            if (row < n) {
#pragma unroll
                for (int nn = 0; nn < 4; nn++) {
                    xp[(size_t)row * 128 + col_base + nn * 16 + lrow] = acc[m][nn][i];
                }
            }
        }
}

// ---------------- Aggregation, layers 2-4: one wave per dst node ----------------
__global__ __launch_bounds__(256) void k_agg(const float* __restrict__ xp, const float* __restrict__ as,
                                             const float* __restrict__ ad, const int* __restrict__ row_ptr,
                                             const int* __restrict__ csr_src, const float* __restrict__ bias,
                                             float* __restrict__ outp,
                                             unsigned* __restrict__ h_hi, unsigned* __restrict__ h_lo,
                                             const float* __restrict__ was_nx, const float* __restrict__ wad_nx,
                                             float* __restrict__ as_nx, float* __restrict__ ad_nx,
                                             int n, int do_relu) {
    __shared__ float2 s_sw[4][64];
    int w = threadIdx.x >> 6, lane = threadIdx.x & 63;
    int node = blockIdx.x * 4 + w;
    if (node >= n) return;
    int s0 = row_ptr[node], s1 = row_ptr[node + 1];
    int deg = s1 - s0;
    float adval = ad[node];
    const float2* xp2 = (const float2*)xp;
    float2 accv = make_float2(0.f, 0.f);
    float den;

    if (deg <= 64) {
        int src = 0;
        float e = -INFINITY;
        if (lane < deg) {
            src = csr_src[s0 + lane];
            float v = as[src] + adval;
            e = LEAKY(v);
        }
        float m = e;
#pragma unroll
        for (int off = 32; off > 0; off >>= 1) m = fmaxf(m, __shfl_xor(m, off, 64));
        float wt = (lane < deg) ? __expf(e - m) : 0.f;
        den = wt;
#pragma unroll
        for (int off = 32; off > 0; off >>= 1) den += __shfl_xor(den, off, 64);
        s_sw[w][lane] = make_float2(__int_as_float(src), wt);
        __builtin_amdgcn_wave_barrier();

        int j = 0;
        for (; j + 4 <= deg; j += 4) {
            float2 p0 = s_sw[w][j + 0];
            float2 p1 = s_sw[w][j + 1];
            float2 p2 = s_sw[w][j + 2];
            float2 p3 = s_sw[w][j + 3];
            float2 v0 = xp2[(size_t)__float_as_int(p0.x) * 64 + lane];
            float2 v1 = xp2[(size_t)__float_as_int(p1.x) * 64 + lane];
            float2 v2 = xp2[(size_t)__float_as_int(p2.x) * 64 + lane];
            float2 v3 = xp2[(size_t)__float_as_int(p3.x) * 64 + lane];
            accv.x += p0.y * v0.x; accv.y += p0.y * v0.y;
            accv.x += p1.y * v1.x; accv.y += p1.y * v1.y;
            accv.x += p2.y * v2.x; accv.y += p2.y * v2.y;
            accv.x += p3.y * v3.x; accv.y += p3.y * v3.y;
        }
        for (; j < deg; j++) {
            float2 p = s_sw[w][j];
            float2 v = xp2[(size_t)__float_as_int(p.x) * 64 + lane];
            accv.x += p.y * v.x; accv.y += p.y * v.y;
        }
    } else {
        float m = -INFINITY;
        for (int i = s0 + lane; i < s1; i += 64) {
            float e = LEAKY(as[csr_src[i]] + adval);
            m = fmaxf(m, e);
        }
#pragma unroll
        for (int off = 32; off > 0; off >>= 1) m = fmaxf(m, __shfl_xor(m, off, 64));
        den = 0.f;
        for (int i = s0; i < s1; i++) {
            int src = csr_src[i];
            float e = LEAKY(as[src] + adval);
            float wt = __expf(e - m);
            den += wt;
            float2 v = xp2[(size_t)src * 64 + lane];
            accv.x += wt * v.x;
            accv.y += wt * v.y;
        }
    }

    float inv = 1.f / (den + 1e-16f);
    float2 b = ((const float2*)bias)[lane];
    float o0 = accv.x * inv + b.x, o1 = accv.y * inv + b.y;
    if (do_relu) { o0 = fmaxf(o0, 0.f); o1 = fmaxf(o1, 0.f); }
    if (outp) ((float2*)outp)[(size_t)node * 64 + lane] = make_float2(o0, o1);
    if (h_hi) {
        ushort hi0 = f32_to_bf16_rne(o0), hi1 = f32_to_bf16_rne(o1);
        float r0 = o0 - bf16_to_f32(hi0), r1 = o1 - bf16_to_f32(hi1);
        h_hi[(size_t)node * 64 + lane] = (unsigned)hi0 | ((unsigned)hi1 << 16);
        h_lo[(size_t)node * 64 + lane] = pack_bf16_pair(r0, r1);
    }
    if (was_nx) {
        int f0 = 2 * lane, f1 = f0 + 1;
        float ps = o0 * was_nx[f0] + o1 * was_nx[f1];
        float pd = o0 * wad_nx[f0] + o1 * wad_nx[f1];
#pragma unroll
        for (int off = 32; off > 0; off >>= 1) {
            ps += __shfl_xor(ps, off, 64);
            pd += __shfl_xor(pd, off, 64);
        }
        if (lane == 0) { as_nx[node] = ps; ad_nx[node] = pd; }
    }
}

// ---------------- launch ----------------

extern "C" void kernel_launch(void* const* d_in, const int* in_sizes, int n_in,
                              void* d_out, int out_size, void* d_ws, size_t ws_size,
                              hipStream_t stream) {
    const float* x     = (const float*)d_in[0];
    const int*   ei    = (const int*)d_in[1];
    const float* W_emb = (const float*)d_in[2];
    const float* b_emb = (const float*)d_in[3];
    const float* W1    = (const float*)d_in[4];
    const float* as1   = (const float*)d_in[5];
    const float* ad1   = (const float*)d_in[6];
    const float* b1    = (const float*)d_in[7];
    const float* Wl[3]  = {(const float*)d_in[8],  (const float*)d_in[12], (const float*)d_in[16]};
    const float* asl[3] = {(const float*)d_in[9],  (const float*)d_in[13], (const float*)d_in[17]};
    const float* adl[3] = {(const float*)d_in[10], (const float*)d_in[14], (const float*)d_in[18]};
    const float* bl[3]  = {(const float*)d_in[11], (const float*)d_in[15], (const float*)d_in[19]};
    float* out = (float*)d_out;

    int N = in_sizes[0];
    int E = in_sizes[1] / 2;
    int Et = E + N;
    int nb = (N + SCAN_BLK - 1) / SCAN_BLK;

    char* ws = (char*)d_ws;
    size_t off = 0;
    auto alloc = [&](size_t bytes) { size_t p = off; off += (bytes + 255) & ~(size_t)255; return p; };
    int*   deg      = (int*)(ws + alloc((size_t)N * 4));
    int*   row_ptr  = (int*)(ws + alloc((size_t)(N + 1) * 4));
    int*   cursor   = (int*)(ws + alloc((size_t)N * 4));
    int*   csr_src  = (int*)(ws + alloc((size_t)Et * 4));
    int*   scantmp  = (int*)(ws + alloc((size_t)N * 4));
    int*   blocksum = (int*)(ws + alloc((size_t)nb * 4));
    int*   blockoff = (int*)(ws + alloc((size_t)nb * 4));
    float* consts   = (float*)(ws + alloc(272 * 4));
    float* S_out    = (float*)(ws + alloc((size_t)N * 4 * 4));
    float* Sw       = (float*)(ws + alloc((size_t)N * 4 * 4));
    float* a_s0     = (float*)(ws + alloc((size_t)N * 4));
    float* a_d0     = (float*)(ws + alloc((size_t)N * 4));
    float* a_s1     = (float*)(ws + alloc((size_t)N * 4));
    float* a_d1     = (float*)(ws + alloc((size_t)N * 4));
    unsigned* h_hi  = (unsigned*)(ws + alloc((size_t)N * 64 * 4));
    unsigned* h_lo  = (unsigned*)(ws + alloc((size_t)N * 64 * 4));
    float* xp       = (float*)(ws + alloc((size_t)N * 128 * 4));
    ushort* wt_hi[3]; ushort* wt_lo[3];
    float* was[3]; float* wad[3];
    for (int l = 0; l < 3; l++) {
        wt_hi[l] = (ushort*)(ws + alloc(128 * 128 * 2));
        wt_lo[l] = (ushort*)(ws + alloc(128 * 128 * 2));
        was[l]   = (float*)(ws + alloc(128 * 4));
        wad[l]   = (float*)(ws + alloc(128 * 4));
    }

    hipMemsetAsync(deg, 0, (size_t)N * 4, stream);
    k_hist<<<(Et + 255) / 256, 256, 0, stream>>>(ei, E, N, deg);
    k_scan1<<<nb, SCAN_BLK, 0, stream>>>(deg, scantmp, blocksum, N);
    k_scan2<<<1, 256, 0, stream>>>(blocksum, blockoff, nb, row_ptr, N);
    k_scan3<<<(N + 255) / 256, 256, 0, stream>>>(scantmp, blockoff, row_ptr, cursor, N);
    k_scatter<<<(Et + 255) / 256, 256, 0, stream>>>(ei, E, N, cursor, csr_src);

    for (int l = 0; l < 3; l++) {
        k_wsplit<<<64, 256, 0, stream>>>(Wl[l], wt_hi[l], wt_lo[l]);
        k_wvec<<<1, 128, 0, stream>>>(Wl[l], asl[l], adl[l], was[l], wad[l]);
    }

    k_emb<<<1, 128, 0, stream>>>(W_emb, b_emb, W1, as1, ad1, consts);
    k_agg1<<<(N + 255) / 256, 256, 0, stream>>>(x, row_ptr, csr_src, consts, S_out, Sw, N);
    k_h1<<<(N + 3) / 4, 256, 0, stream>>>(S_out, Sw, consts, b1, was[0], wad[0],
                                          h_hi, h_lo, a_s0, a_d0, N);

    float* as_cur = a_s0; float* ad_cur = a_d0;
    float* as_nxt = a_s1; float* ad_nxt = a_d1;
    for (int l = 0; l < 3; l++) {
        k_gemm_mfma<<<(N + 127) / 128, 256, 0, stream>>>(
            (const ushort*)h_hi, (const ushort*)h_lo, wt_hi[l], wt_lo[l], xp, N);
        if (l < 2) {
            k_agg<<<(N + 3) / 4, 256, 0, stream>>>(
                xp, as_cur, ad_cur, row_ptr, csr_src, bl[l],
                nullptr, h_hi, h_lo, was[l + 1], wad[l + 1], as_nxt, ad_nxt, N, 1);
            float* t;
            t = as_cur; as_cur = as_nxt; as_nxt = t;
            t = ad_cur; ad_cur = ad_nxt; ad_nxt = t;
        } else {
            k_agg<<<(N + 3) / 4, 256, 0, stream>>>(
                xp, as_cur, ad_cur, row_ptr, csr_src, bl[l],
                out, nullptr, nullptr, nullptr, nullptr, nullptr, nullptr, N, 0);
        }
    }
}